// Round 2
// baseline (940.942 us; speedup 1.0000x reference)
//
#include <hip/hip_runtime.h>

#define HID 8
#define TSTEPS 1024
#define BATCH 16384

// Broadcast lane (group_base | K) within each 8-lane group (compile-time swizzle).
template<int K>
__device__ __forceinline__ float bc8(float v) {
    return __int_as_float(__builtin_amdgcn_ds_swizzle(__float_as_int(v), (K << 5) | 0x18));
}

__device__ __forceinline__ void gather8(float* d, float v) {
    d[0] = bc8<0>(v); d[1] = bc8<1>(v); d[2] = bc8<2>(v); d[3] = bc8<3>(v);
    d[4] = bc8<4>(v); d[5] = bc8<5>(v); d[6] = bc8<6>(v); d[7] = bc8<7>(v);
}

__device__ __forceinline__ float fsig(float x) {
    float e = __builtin_amdgcn_exp2f(x * -1.44269504f);   // exp(-x)
    return __builtin_amdgcn_rcpf(1.0f + e);
}
__device__ __forceinline__ float ftanh(float x) {
    float e = __builtin_amdgcn_exp2f(x * -2.88539008f);   // exp(-2x)
    return __builtin_fmaf(2.0f, __builtin_amdgcn_rcpf(1.0f + e), -1.0f);
}

__global__ __launch_bounds__(256) void lstm2_fused(
    const float* __restrict__ x,
    const float* __restrict__ w_ih_l0, const float* __restrict__ w_hh_l0,
    const float* __restrict__ b_ih_l0, const float* __restrict__ b_hh_l0,
    const float* __restrict__ w_ih_l1, const float* __restrict__ w_hh_l1,
    const float* __restrict__ b_ih_l1, const float* __restrict__ b_hh_l1,
    const float* __restrict__ fc_w, const float* __restrict__ fc_b,
    float* __restrict__ out)
{
    const int tid = blockIdx.x * blockDim.x + threadIdx.x;
    const int j = tid & 7;       // hidden unit owned by this lane
    const int b = tid >> 3;      // batch element (8 lanes per batch elem)

    // Per-lane weights: row (g*8+j) of each matrix, g = gate {i,f,g,o}.
    float wi0x[4], wi0y[4], wh0[4][8], zb0[4];
    float wi1[4][8], wh1[4][8], zb1[4];
#pragma unroll
    for (int g = 0; g < 4; ++g) {
        const int r = g * 8 + j;
        wi0x[g] = w_ih_l0[r * 2 + 0];
        wi0y[g] = w_ih_l0[r * 2 + 1];
        zb0[g]  = b_ih_l0[r] + b_hh_l0[r];
        zb1[g]  = b_ih_l1[r] + b_hh_l1[r];
#pragma unroll
        for (int k = 0; k < 8; ++k) {
            wh0[g][k] = w_hh_l0[r * 8 + k];
            wi1[g][k] = w_ih_l1[r * 8 + k];
            wh1[g][k] = w_hh_l1[r * 8 + k];
        }
    }
    const float fcw = fc_w[j];
    const float fcb = fc_b[0];

    float h0 = 0.f, c0 = 0.f, h1 = 0.f, c1 = 0.f;

    // x[t][b][0:2] as float2; stride between timesteps = BATCH float2s.
    const float2* xp = reinterpret_cast<const float2*>(x) + b;
    float2 xv = xp[0];
    float2 xn = xp[BATCH];

    for (int t = 0; t < TSTEPS; ++t) {
        float2 xn2 = (t + 2 < TSTEPS) ? xp[2 * BATCH] : xv;  // 2-deep prefetch
        xp += BATCH;

        // Broadcast current h0, h1 across the 8-lane group.
        float h0v[8], h1v[8];
        gather8(h0v, h0);
        gather8(h1v, h1);

        float z0[4], z1[4];
#pragma unroll
        for (int g = 0; g < 4; ++g) {
            z0[g] = __builtin_fmaf(wi0y[g], xv.y, __builtin_fmaf(wi0x[g], xv.x, zb0[g]));
            z1[g] = zb1[g];   // start layer-1 z with its h1-recurrent part (hides swizzle latency)
#pragma unroll
            for (int k = 0; k < 8; ++k) {
                z0[g] = __builtin_fmaf(wh0[g][k], h0v[k], z0[g]);
                z1[g] = __builtin_fmaf(wh1[g][k], h1v[k], z1[g]);
            }
        }
        const float gi = fsig(z0[0]), gf = fsig(z0[1]);
        const float gg = ftanh(z0[2]), go = fsig(z0[3]);
        c0 = __builtin_fmaf(gf, c0, gi * gg);
        h0 = go * ftanh(c0);

        // Broadcast new layer-0 h, finish layer-1 z.
        float h0n[8];
        gather8(h0n, h0);
#pragma unroll
        for (int g = 0; g < 4; ++g) {
#pragma unroll
            for (int k = 0; k < 8; ++k)
                z1[g] = __builtin_fmaf(wi1[g][k], h0n[k], z1[g]);
        }
        const float i1 = fsig(z1[0]), f1 = fsig(z1[1]);
        const float g1 = ftanh(z1[2]), o1 = fsig(z1[3]);
        c1 = __builtin_fmaf(f1, c1, i1 * g1);
        h1 = o1 * ftanh(c1);

        xv = xn; xn = xn2;
    }

    // out[b] = fc_b + sum_j fc_w[j] * h1[j]  (reduce within the 8-lane group)
    float p = fcw * h1;
    p += __shfl_xor(p, 1);
    p += __shfl_xor(p, 2);
    p += __shfl_xor(p, 4);
    if (j == 0) out[b] = p + fcb;
}

extern "C" void kernel_launch(void* const* d_in, const int* in_sizes, int n_in,
                              void* d_out, int out_size, void* d_ws, size_t ws_size,
                              hipStream_t stream) {
    const float* x       = (const float*)d_in[0];
    const float* w_ih_l0 = (const float*)d_in[1];
    const float* w_hh_l0 = (const float*)d_in[2];
    const float* b_ih_l0 = (const float*)d_in[3];
    const float* b_hh_l0 = (const float*)d_in[4];
    const float* w_ih_l1 = (const float*)d_in[5];
    const float* w_hh_l1 = (const float*)d_in[6];
    const float* b_ih_l1 = (const float*)d_in[7];
    const float* b_hh_l1 = (const float*)d_in[8];
    const float* fc_w    = (const float*)d_in[9];
    const float* fc_b    = (const float*)d_in[10];
    float* out = (float*)d_out;

    const int threads = 256;
    const int blocks  = (BATCH * 8) / threads;  // 512
    lstm2_fused<<<blocks, threads, 0, stream>>>(
        x, w_ih_l0, w_hh_l0, b_ih_l0, b_hh_l0,
        w_ih_l1, w_hh_l1, b_ih_l1, b_hh_l1, fc_w, fc_b, out);
}

// Round 3
// 934.713 us; speedup vs baseline: 1.0067x; 1.0067x over previous
//
#include <hip/hip_runtime.h>

#define TSTEPS 1024
#define BATCH 16384

// Broadcast lane (group_base | K) within each 8-lane group (compile-time swizzle).
// offset = (xor<<10)|(or<<5)|and ; src = ((lane & 0x18) | K)  -> verified absmax 0.0 in round 2.
template<int K>
__device__ __forceinline__ float bc8(float v) {
    return __int_as_float(__builtin_amdgcn_ds_swizzle(__float_as_int(v), (K << 5) | 0x18));
}
__device__ __forceinline__ void gather8(float* d, float v) {
    d[0] = bc8<0>(v); d[1] = bc8<1>(v); d[2] = bc8<2>(v); d[3] = bc8<3>(v);
    d[4] = bc8<4>(v); d[5] = bc8<5>(v); d[6] = bc8<6>(v); d[7] = bc8<7>(v);
}

// Activations on PRE-SCALED inputs: z already multiplied by -log2(e) (sigmoid)
// or -2*log2(e) (tanh), folded into the weights/biases at load time.
__device__ __forceinline__ float sig_s(float zs) {   // sigmoid(x), zs = -x*log2e
    return __builtin_amdgcn_rcpf(1.0f + __builtin_amdgcn_exp2f(zs));
}
__device__ __forceinline__ float tanh_s(float zs) {  // tanh(x), zs = -2x*log2e
    return __builtin_fmaf(2.0f, __builtin_amdgcn_rcpf(1.0f + __builtin_amdgcn_exp2f(zs)), -1.0f);
}
__device__ __forceinline__ float tanh_raw(float c) {
    return tanh_s(c * -2.88539008f);
}

__global__ __launch_bounds__(256, 2) void lstm2_fused(
    const float* __restrict__ x,
    const float* __restrict__ w_ih_l0, const float* __restrict__ w_hh_l0,
    const float* __restrict__ b_ih_l0, const float* __restrict__ b_hh_l0,
    const float* __restrict__ w_ih_l1, const float* __restrict__ w_hh_l1,
    const float* __restrict__ b_ih_l1, const float* __restrict__ b_hh_l1,
    const float* __restrict__ fc_w, const float* __restrict__ fc_b,
    float* __restrict__ out)
{
    const int tid = blockIdx.x * blockDim.x + threadIdx.x;
    const int j = tid & 7;       // hidden unit owned by this lane
    const int b = tid >> 3;      // batch element (8 lanes per batch elem)

    // Gate order i,f,g,o. Pre-scale: sigmoid rows by -log2e, tanh(g) rows by -2log2e.
    const float sc[4] = {-1.44269504f, -1.44269504f, -2.88539008f, -1.44269504f};

    float wi0x[4], wi0y[4], wh0[4][8], zb0[4];
    float wi1[4][8], wh1[4][8], zb1[4];
#pragma unroll
    for (int g = 0; g < 4; ++g) {
        const int r = g * 8 + j;
        const float s = sc[g];
        wi0x[g] = s * w_ih_l0[r * 2 + 0];
        wi0y[g] = s * w_ih_l0[r * 2 + 1];
        zb0[g]  = s * (b_ih_l0[r] + b_hh_l0[r]);
        zb1[g]  = s * (b_ih_l1[r] + b_hh_l1[r]);
#pragma unroll
        for (int k = 0; k < 8; ++k) {
            wh0[g][k] = s * w_hh_l0[r * 8 + k];
            wi1[g][k] = s * w_ih_l1[r * 8 + k];
            wh1[g][k] = s * w_hh_l1[r * 8 + k];
        }
    }
    const float fcw = fc_w[j];     // NOT pre-scaled
    const float fcb = fc_b[0];

    float h0 = 0.f, c0 = 0.f, h1 = 0.f, c1 = 0.f;
    // Persistent broadcast vectors: h0v/h1v carry the gathers done inside the
    // previous iteration (software pipeline: gather overlaps next step's FMAs).
    float h0v[8], h1v[8];
#pragma unroll
    for (int k = 0; k < 8; ++k) { h0v[k] = 0.f; h1v[k] = 0.f; }

    // x[t][b][0:2] as float2; stride between timesteps = BATCH float2s.
    const float2* xp = reinterpret_cast<const float2*>(x) + b;
    float2 xv = xp[0];
    float2 xn = xp[BATCH];

    for (int t = 0; t < TSTEPS; ++t) {
        float2 xn2 = (t + 2 < TSTEPS) ? xp[2 * BATCH] : xv;  // 2-deep prefetch
        xp += BATCH;

        float z0[4], z1[4];
#pragma unroll
        for (int g = 0; g < 4; ++g) {
            z0[g] = __builtin_fmaf(wi0y[g], xv.y, __builtin_fmaf(wi0x[g], xv.x, zb0[g]));
            z1[g] = zb1[g];
#pragma unroll
            for (int k = 0; k < 8; ++k) {
                z0[g] = __builtin_fmaf(wh0[g][k], h0v[k], z0[g]);
                z1[g] = __builtin_fmaf(wh1[g][k], h1v[k], z1[g]);
            }
        }
        const float gi = sig_s(z0[0]), gf = sig_s(z0[1]);
        const float gg = tanh_s(z0[2]), go = sig_s(z0[3]);
        c0 = __builtin_fmaf(gf, c0, gi * gg);
        h0 = go * tanh_raw(c0);

        gather8(h0v, h0);            // new h0 broadcast (reused next iter for z0)
#pragma unroll
        for (int g = 0; g < 4; ++g) {
#pragma unroll
            for (int k = 0; k < 8; ++k)
                z1[g] = __builtin_fmaf(wi1[g][k], h0v[k], z1[g]);
        }
        const float i1 = sig_s(z1[0]), f1 = sig_s(z1[1]);
        const float g1 = tanh_s(z1[2]), o1 = sig_s(z1[3]);
        c1 = __builtin_fmaf(f1, c1, i1 * g1);
        h1 = o1 * tanh_raw(c1);

        gather8(h1v, h1);            // overlaps next iteration's z0 FMAs

        xv = xn; xn = xn2;
    }

    // out[b] = fc_b + sum_j fc_w[j] * h1[j]  (reduce within the 8-lane group)
    float p = fcw * h1;
    p += __shfl_xor(p, 1);
    p += __shfl_xor(p, 2);
    p += __shfl_xor(p, 4);
    if (j == 0) out[b] = p + fcb;
}

extern "C" void kernel_launch(void* const* d_in, const int* in_sizes, int n_in,
                              void* d_out, int out_size, void* d_ws, size_t ws_size,
                              hipStream_t stream) {
    const float* x       = (const float*)d_in[0];
    const float* w_ih_l0 = (const float*)d_in[1];
    const float* w_hh_l0 = (const float*)d_in[2];
    const float* b_ih_l0 = (const float*)d_in[3];
    const float* b_hh_l0 = (const float*)d_in[4];
    const float* w_ih_l1 = (const float*)d_in[5];
    const float* w_hh_l1 = (const float*)d_in[6];
    const float* b_ih_l1 = (const float*)d_in[7];
    const float* b_hh_l1 = (const float*)d_in[8];
    const float* fc_w    = (const float*)d_in[9];
    const float* fc_b    = (const float*)d_in[10];
    float* out = (float*)d_out;

    const int threads = 256;
    const int blocks  = (BATCH * 8) / threads;  // 512 blocks = 2048 waves = 2/SIMD
    lstm2_fused<<<blocks, threads, 0, stream>>>(
        x, w_ih_l0, w_hh_l0, b_ih_l0, b_hh_l0,
        w_ih_l1, w_hh_l1, b_ih_l1, b_hh_l1, fc_w, fc_b, out);
}

// Round 4
// 927.527 us; speedup vs baseline: 1.0145x; 1.0077x over previous
//
#include <hip/hip_runtime.h>

#define TSTEPS 1024
#define BATCH 16384

typedef float f32x2 __attribute__((ext_vector_type(2)));

// Broadcast lane ((lane & 0x18) | K) within each 8-lane group — verified absmax 0.0.
template<int K>
__device__ __forceinline__ float bc8(float v) {
    return __int_as_float(__builtin_amdgcn_ds_swizzle(__float_as_int(v), (K << 5) | 0x18));
}
__device__ __forceinline__ void gather8(float* d, float v) {
    d[0] = bc8<0>(v); d[1] = bc8<1>(v); d[2] = bc8<2>(v); d[3] = bc8<3>(v);
    d[4] = bc8<4>(v); d[5] = bc8<5>(v); d[6] = bc8<6>(v); d[7] = bc8<7>(v);
}

__device__ __forceinline__ f32x2 fma2(f32x2 a, f32x2 b, f32x2 c) {
    return __builtin_elementwise_fma(a, b, c);   // v_pk_fma_f32
}
__device__ __forceinline__ f32x2 splat2(float v) { f32x2 r; r.x = v; r.y = v; return r; }

// Activations on PRE-SCALED inputs (weights folded with -log2e / -2log2e).
__device__ __forceinline__ float sig_s(float zs) {   // sigmoid(x), zs = -x*log2e
    return __builtin_amdgcn_rcpf(1.0f + __builtin_amdgcn_exp2f(zs));
}
__device__ __forceinline__ float tanh_s(float zs) {  // tanh(x), zs = -2x*log2e
    return __builtin_fmaf(2.0f, __builtin_amdgcn_rcpf(1.0f + __builtin_amdgcn_exp2f(zs)), -1.0f);
}
__device__ __forceinline__ float tanh_raw(float c) { return tanh_s(c * -2.88539008f); }

__global__ __launch_bounds__(256, 2) void lstm2_fused(
    const float* __restrict__ x,
    const float* __restrict__ w_ih_l0, const float* __restrict__ w_hh_l0,
    const float* __restrict__ b_ih_l0, const float* __restrict__ b_hh_l0,
    const float* __restrict__ w_ih_l1, const float* __restrict__ w_hh_l1,
    const float* __restrict__ b_ih_l1, const float* __restrict__ b_hh_l1,
    const float* __restrict__ fc_w, const float* __restrict__ fc_b,
    float* __restrict__ out)
{
    const int tid = blockIdx.x * blockDim.x + threadIdx.x;
    const int j = tid & 7;       // hidden unit owned by this lane
    const int b = tid >> 3;      // batch element (8 lanes per batch elem)

    // Gate order i,f,g,o. Pre-scale: sigmoid rows by -log2e, tanh(g) rows by -2log2e.
    const float sc[4] = {-1.44269504f, -1.44269504f, -2.88539008f, -1.44269504f};

    // Packed per-lane weights: pair p holds gates (2p, 2p+1) in (x, y).
    f32x2 wi0xp[2], wi0yp[2], zb0p[2], zb1p[2];
    f32x2 wh0p[2][8], wi1p[2][8], wh1p[2][8];
#pragma unroll
    for (int p = 0; p < 2; ++p) {
        const int ga = 2 * p, gb = 2 * p + 1;
        const int ra = ga * 8 + j, rb = gb * 8 + j;
        const float sa = sc[ga], sb = sc[gb];
        wi0xp[p].x = sa * w_ih_l0[ra * 2 + 0]; wi0xp[p].y = sb * w_ih_l0[rb * 2 + 0];
        wi0yp[p].x = sa * w_ih_l0[ra * 2 + 1]; wi0yp[p].y = sb * w_ih_l0[rb * 2 + 1];
        zb0p[p].x = sa * (b_ih_l0[ra] + b_hh_l0[ra]);
        zb0p[p].y = sb * (b_ih_l0[rb] + b_hh_l0[rb]);
        zb1p[p].x = sa * (b_ih_l1[ra] + b_hh_l1[ra]);
        zb1p[p].y = sb * (b_ih_l1[rb] + b_hh_l1[rb]);
#pragma unroll
        for (int k = 0; k < 8; ++k) {
            wh0p[p][k].x = sa * w_hh_l0[ra * 8 + k]; wh0p[p][k].y = sb * w_hh_l0[rb * 8 + k];
            wi1p[p][k].x = sa * w_ih_l1[ra * 8 + k]; wi1p[p][k].y = sb * w_ih_l1[rb * 8 + k];
            wh1p[p][k].x = sa * w_hh_l1[ra * 8 + k]; wh1p[p][k].y = sb * w_hh_l1[rb * 8 + k];
        }
    }
    // PIN all weights in VGPRs: opaque asm output -> compiler cannot re-load
    // them from global inside the t-loop (this was the round-3 2x: VGPR=76,
    // weight loads sunk into the loop).
#pragma unroll
    for (int p = 0; p < 2; ++p) {
        asm volatile("" : "+v"(wi0xp[p]), "+v"(wi0yp[p]), "+v"(zb0p[p]), "+v"(zb1p[p]));
#pragma unroll
        for (int k = 0; k < 8; ++k)
            asm volatile("" : "+v"(wh0p[p][k]), "+v"(wi1p[p][k]), "+v"(wh1p[p][k]));
    }
    const float fcw = fc_w[j];     // NOT pre-scaled
    const float fcb = fc_b[0];

    float h0 = 0.f, c0 = 0.f, h1 = 0.f, c1 = 0.f;
    // h broadcasts carried across iterations (gather overlaps next step's FMAs).
    float h0v[8], h1v[8];
#pragma unroll
    for (int k = 0; k < 8; ++k) { h0v[k] = 0.f; h1v[k] = 0.f; }

    const float2* xp = reinterpret_cast<const float2*>(x) + b;
    float2 xv = xp[0];
    float2 xn = xp[BATCH];

    for (int t = 0; t < TSTEPS; ++t) {
        float2 xn2 = (t + 2 < TSTEPS) ? xp[2 * BATCH] : xv;  // 2-deep prefetch
        xp += BATCH;

        f32x2 z0[2], z1[2];
#pragma unroll
        for (int p = 0; p < 2; ++p) {
            z0[p] = fma2(wi0yp[p], splat2(xv.y), fma2(wi0xp[p], splat2(xv.x), zb0p[p]));
            z1[p] = zb1p[p];
#pragma unroll
            for (int k = 0; k < 8; ++k) {
                z0[p] = fma2(wh0p[p][k], splat2(h0v[k]), z0[p]);
                z1[p] = fma2(wh1p[p][k], splat2(h1v[k]), z1[p]);
            }
        }
        const float gi = sig_s(z0[0].x), gf = sig_s(z0[0].y);
        const float gg = tanh_s(z0[1].x), go = sig_s(z0[1].y);
        c0 = __builtin_fmaf(gf, c0, gi * gg);
        h0 = go * tanh_raw(c0);

        gather8(h0v, h0);            // reused next iter for z0
#pragma unroll
        for (int p = 0; p < 2; ++p)
#pragma unroll
            for (int k = 0; k < 8; ++k)
                z1[p] = fma2(wi1p[p][k], splat2(h0v[k]), z1[p]);

        const float i1 = sig_s(z1[0].x), f1 = sig_s(z1[0].y);
        const float g1 = tanh_s(z1[1].x), o1 = sig_s(z1[1].y);
        c1 = __builtin_fmaf(f1, c1, i1 * g1);
        h1 = o1 * tanh_raw(c1);

        gather8(h1v, h1);            // overlaps next iteration's z0 FMAs

        xv = xn; xn = xn2;
    }

    // out[b] = fc_b + sum_j fc_w[j] * h1[j]
    float p = fcw * h1;
    p += __shfl_xor(p, 1);
    p += __shfl_xor(p, 2);
    p += __shfl_xor(p, 4);
    if (j == 0) out[b] = p + fcb;
}

extern "C" void kernel_launch(void* const* d_in, const int* in_sizes, int n_in,
                              void* d_out, int out_size, void* d_ws, size_t ws_size,
                              hipStream_t stream) {
    const float* x       = (const float*)d_in[0];
    const float* w_ih_l0 = (const float*)d_in[1];
    const float* w_hh_l0 = (const float*)d_in[2];
    const float* b_ih_l0 = (const float*)d_in[3];
    const float* b_hh_l0 = (const float*)d_in[4];
    const float* w_ih_l1 = (const float*)d_in[5];
    const float* w_hh_l1 = (const float*)d_in[6];
    const float* b_ih_l1 = (const float*)d_in[7];
    const float* b_hh_l1 = (const float*)d_in[8];
    const float* fc_w    = (const float*)d_in[9];
    const float* fc_b    = (const float*)d_in[10];
    float* out = (float*)d_out;

    const int threads = 256;
    const int blocks  = (BATCH * 8) / threads;  // 512 blocks = 2048 waves = 2/SIMD
    lstm2_fused<<<blocks, threads, 0, stream>>>(
        x, w_ih_l0, w_hh_l0, b_ih_l0, b_hh_l0,
        w_ih_l1, w_hh_l1, b_ih_l1, b_hh_l1, fc_w, fc_b, out);
}